// Round 5
// baseline (898.182 us; speedup 1.0000x reference)
//
#include <hip/hip_runtime.h>

typedef __attribute__((ext_vector_type(8))) short bf16x8;
typedef __attribute__((ext_vector_type(4))) float f32x4;
typedef __attribute__((ext_vector_type(8))) unsigned short u16x8;

#define BAR() __builtin_amdgcn_s_barrier()
#define VMC(n) asm volatile("s_waitcnt vmcnt(" #n ")" ::: "memory")
#define SB0() __builtin_amdgcn_sched_barrier(0)
#define WAITL() do { asm volatile("s_waitcnt lgkmcnt(0)"); SB0(); } while (0)
#define DSRI(dst, base, imm) \
  asm volatile("ds_read_b128 %0, %1 offset:%2" : "=&v"(dst) : "v"(base), "i"(imm))

__device__ inline unsigned short f2bf(float f) {
  unsigned int u = __float_as_uint(f);
  u += 0x7fffu + ((u >> 16) & 1u);
  return (unsigned short)(u >> 16);
}

__device__ inline void gload_lds16(const void* g, void* l) {
  __builtin_amdgcn_global_load_lds(
      (const __attribute__((address_space(1))) void*)g,
      (__attribute__((address_space(3))) void*)l, 16, 0, 0);
}

// ---------------- weight transpose + bf16 cast: W[K][N] -> Wt[N][K] ----------
__global__ void wtrans(const float* __restrict__ W, unsigned short* __restrict__ Wt,
                       int K, int N) {
  int idx = blockIdx.x * 256 + threadIdx.x;
  if (idx >= K * N) return;
  int k = idx / N, n = idx - k * N;
  Wt[(size_t)n * K + k] = f2bf(W[idx]);
}

// ---------------- LayerNorm (+ optional shift/window gather), f32 -> bf16 ----
template <int MODE>
__global__ void ln_k(const float* __restrict__ x, const float* __restrict__ sc,
                     const float* __restrict__ bi, unsigned short* __restrict__ o) {
  int t = blockIdx.x * 4 + (threadIdx.x >> 6);
  int l = threadIdx.x & 63;
  size_t src;
  if (MODE == 0) {
    int b = t / 28800, r = t - b * 28800;
    int win = r / 144, tok = r - win * 144;
    int c1 = win / 100, rem = win - c1 * 100;
    int h1 = rem / 10, w1 = rem - h1 * 10;
    int tc = tok / 72, tr = tok - tc * 72;
    int th = tr / 12, tw = tr - th * 12;
    int cs = c1 * 2 + tc, hs = h1 * 6 + th, wsp = w1 * 12 + tw;
    int co = (cs + 1) & 3;
    int ho = hs + 3; if (ho >= 60) ho -= 60;
    int wo = wsp + 6; if (wo >= 120) wo -= 120;
    src = ((size_t)b * 28800 + (co * 60 + ho) * 120 + wo) * 512;
  } else {
    src = (size_t)t * 512;
  }
  const float4* xr = (const float4*)(x + src);
  float4 v0 = xr[l * 2], v1 = xr[l * 2 + 1];
  float s = v0.x + v0.y + v0.z + v0.w + v1.x + v1.y + v1.z + v1.w;
  float s2 = v0.x * v0.x + v0.y * v0.y + v0.z * v0.z + v0.w * v0.w +
             v1.x * v1.x + v1.y * v1.y + v1.z * v1.z + v1.w * v1.w;
  #pragma unroll
  for (int o2 = 32; o2; o2 >>= 1) {
    s += __shfl_xor(s, o2);
    s2 += __shfl_xor(s2, o2);
  }
  float mean = s * (1.0f / 512.0f);
  float var = s2 * (1.0f / 512.0f) - mean * mean;
  float inv = rsqrtf(var + 1e-6f);
  const float4* scp = (const float4*)sc;
  const float4* bip = (const float4*)bi;
  float4 sa = scp[l * 2], sb = scp[l * 2 + 1];
  float4 ba = bip[l * 2], bb = bip[l * 2 + 1];
  u16x8 ov;
  ov[0] = f2bf((v0.x - mean) * inv * sa.x + ba.x);
  ov[1] = f2bf((v0.y - mean) * inv * sa.y + ba.y);
  ov[2] = f2bf((v0.z - mean) * inv * sa.z + ba.z);
  ov[3] = f2bf((v0.w - mean) * inv * sa.w + ba.w);
  ov[4] = f2bf((v1.x - mean) * inv * sb.x + bb.x);
  ov[5] = f2bf((v1.y - mean) * inv * sb.y + bb.y);
  ov[6] = f2bf((v1.z - mean) * inv * sb.z + bb.z);
  ov[7] = f2bf((v1.w - mean) * inv * sb.w + bb.w);
  *(u16x8*)&o[(size_t)t * 512 + l * 8] = ov;
}

// ---------------- 128x256 bf16 MFMA GEMM: A via LDS ring, B direct to regs --
// A: M x K row-major bf16.  Bt: N x K row-major bf16.
// 256 threads / 4 waves; per-wave output 128 x 64.
// LDS: 3 ring slots x (A 128x32) = 24 KiB only.  B fragments are loaded
// straight from global (L2-resident weight panels) into registers,
// double-buffered one chunk ahead (bP/bN, 2-chunk-unrolled loop).
// Per chunk: 8x ds_read_b128 (A frags) | stage A(t+2) (2x gload_lds) |
// load B(t+1) (4x dwordx4) | vmcnt(6) | lgkm(0) | 32 MFMA | s_barrier.
template <int EPI>
__launch_bounds__(256, 2)
__global__ void gemmB(const unsigned short* __restrict__ A,
                      const unsigned short* __restrict__ Bt,
                      const float* __restrict__ bias, void* __restrict__ outp,
                      const float* __restrict__ res, int M, int N, int K) {
  __shared__ __attribute__((aligned(16))) unsigned short ldsA[3][4096];
  const int tid = threadIdx.x;
  const int w = tid >> 6, l = tid & 63;
  const int lane15 = l & 15, lk = (l >> 4) << 3;
  const int ntile = N >> 8;
  // bijective XCD-aware swizzle (m204)
  const int nwg = gridDim.x;
  const int q = nwg >> 3, r = nwg & 7;
  const int xcd = blockIdx.x & 7, idx8 = blockIdx.x >> 3;
  const int wgid = (xcd < r ? xcd * (q + 1) : r * (q + 1) + (xcd - r) * q) + idx8;
  const int bm = wgid / ntile, bn = wgid - bm * ntile;
  const int KT = K >> 5;  // number of K=32 chunks (always even here)

  // ---- A staging offsets (store-side swizzle) ----
  const int swzb = ((l >> 3) & 3) << 3;
  const int colx = (((l & 3) << 3) ^ swzb);
  const int offA0 = ((w * 16 + (l >> 2)) * K + colx) * 2;
  const int offA1 = (((4 + w) * 16 + (l >> 2)) * K + colx) * 2;

  // ---- A LDS read bases (read-side swizzle) ----
  const int sw = ((lane15 >> 1) & 3) << 3;
  unsigned lds0 = (unsigned)(unsigned long long)
      (__attribute__((address_space(3))) void*)(void*)&ldsA[0][0];
  unsigned bA0 = lds0 + (unsigned)(lane15 * 64 + ((lk ^ sw) << 1));
  unsigned bA1 = bA0 + 8192u, bA2 = bA0 + 16384u;
  unsigned short* p0 = &ldsA[0][0];
  unsigned short* p1 = &ldsA[1][0];
  unsigned short* p2 = &ldsA[2][0];

  const char* gA = (const char*)(A + (size_t)bm * 128 * K);

  // ---- B direct-load per-lane pointers (4 fragments) ----
  const unsigned short* gBf[4];
  #pragma unroll
  for (int nf = 0; nf < 4; ++nf)
    gBf[nf] = Bt + (size_t)(bn * 256 + w * 64 + nf * 16 + lane15) * K + lk;

  f32x4 acc[8][4] = {};
  bf16x8 af[8], bP[4], bN[4];

  auto STAGEA = [&](unsigned short* pS, const char* ga) {
    gload_lds16(ga + offA0, pS + w * 512);
    gload_lds16(ga + offA1, pS + 2048 + w * 512);
  };
  auto MFMA32 = [&](bf16x8* bu) {
    __builtin_amdgcn_s_setprio(1);
    #pragma unroll
    for (int mi = 0; mi < 8; ++mi)
      #pragma unroll
      for (int nf = 0; nf < 4; ++nf)
        acc[mi][nf] = __builtin_amdgcn_mfma_f32_16x16x32_bf16(
            af[mi], bu[nf], acc[mi][nf], 0, 0, 0);
    __builtin_amdgcn_s_setprio(0);
  };

  // prologue: stage A chunks 0,1; load B chunk 0
  STAGEA(p0, gA);
  STAGEA(p1, gA + 64);
  gA += 128;
  #pragma unroll
  for (int nf = 0; nf < 4; ++nf) { bP[nf] = *(const bf16x8*)gBf[nf]; gBf[nf] += 32; }
  VMC(0);
  BAR();

  for (int t = 0; t < KT; t += 2) {
    // ---- chunk t: A in slot bA0/p0, use bP, load bN(t+1), stage A(t+2) ----
    DSRI(af[0], bA0, 0);    DSRI(af[1], bA0, 1024);
    DSRI(af[2], bA0, 2048); DSRI(af[3], bA0, 3072);
    DSRI(af[4], bA0, 4096); DSRI(af[5], bA0, 5120);
    DSRI(af[6], bA0, 6144); DSRI(af[7], bA0, 7168);
    if (t + 2 < KT) { STAGEA(p2, gA); gA += 64; }
    if (t + 1 < KT) {
      #pragma unroll
      for (int nf = 0; nf < 4; ++nf) { bN[nf] = *(const bf16x8*)gBf[nf]; gBf[nf] += 32; }
    }
    if (t + 2 < KT) { VMC(6); } else if (t + 1 < KT) { VMC(4); } else { VMC(0); }
    WAITL();
    MFMA32(bP);
    BAR();
    { unsigned ta = bA0; bA0 = bA1; bA1 = bA2; bA2 = ta;
      unsigned short* tp = p0; p0 = p1; p1 = p2; p2 = tp; }
    // ---- chunk t+1: use bN, load bP(t+2), stage A(t+3) ----
    DSRI(af[0], bA0, 0);    DSRI(af[1], bA0, 1024);
    DSRI(af[2], bA0, 2048); DSRI(af[3], bA0, 3072);
    DSRI(af[4], bA0, 4096); DSRI(af[5], bA0, 5120);
    DSRI(af[6], bA0, 6144); DSRI(af[7], bA0, 7168);
    if (t + 3 < KT) { STAGEA(p2, gA); gA += 64; }
    if (t + 2 < KT) {
      #pragma unroll
      for (int nf = 0; nf < 4; ++nf) { bP[nf] = *(const bf16x8*)gBf[nf]; gBf[nf] += 32; }
    }
    if (t + 3 < KT) { VMC(6); } else if (t + 2 < KT) { VMC(4); } else { VMC(0); }
    WAITL();
    MFMA32(bN);
    BAR();
    { unsigned ta = bA0; bA0 = bA1; bA1 = bA2; bA2 = ta;
      unsigned short* tp = p0; p0 = p1; p1 = p2; p2 = tp; }
  }

  // ---------------- epilogue ----------------
  float* outf = (float*)outp;
  unsigned short* outh = (unsigned short*)outp;
  #pragma unroll
  for (int mi = 0; mi < 8; ++mi) {
    #pragma unroll
    for (int j = 0; j < 4; ++j) {
      int grow = bm * 128 + mi * 16 + ((l >> 4) << 2) + j;
      int win = 0, tok = 0;
      size_t rowbase = 0;
      if constexpr (EPI == 0) {
        win = grow / 144;
        tok = grow - win * 144;
      } else if constexpr (EPI == 1) {
        win = grow / 144;
        tok = grow - win * 144;
        int b = win / 200, wl = win - b * 200;
        int c1 = wl / 100, rem = wl - c1 * 100;
        int h1 = rem / 10, w1 = rem - h1 * 10;
        int tc = tok / 72, tr = tok - tc * 72;
        int th = tr / 12, tw = tr - th * 12;
        int cs = c1 * 2 + tc, hs = h1 * 6 + th, wsp = w1 * 12 + tw;
        int co = (cs + 1) & 3;
        int ho = hs + 3; if (ho >= 60) ho -= 60;
        int wo = wsp + 6; if (wo >= 120) wo -= 120;
        rowbase = ((size_t)b * 28800 + (co * 60 + ho) * 120 + wo) * 512;
      }
      #pragma unroll
      for (int nf = 0; nf < 4; ++nf) {
        int gcol = bn * 256 + w * 64 + nf * 16 + lane15;
        float val = acc[mi][nf][j] + bias[gcol];
        if constexpr (EPI == 0) {
          int which = gcol >> 9, hd = (gcol >> 6) & 7, dh = gcol & 63;
          outh[(((size_t)(win * 3 + which) * 8 + hd) * 144 + tok) * 64 + dh] = f2bf(val);
        } else if constexpr (EPI == 1) {
          size_t oi = rowbase + gcol;
          outf[oi] = res[oi] + val;
        } else if constexpr (EPI == 2) {
          float u = 0.7978845608f * (val + 0.044715f * val * val * val);
          float g = val / (1.0f + __expf(-2.0f * u));
          outh[(size_t)grow * N + gcol] = f2bf(g);
        } else {
          size_t oi = (size_t)grow * N + gcol;
          outf[oi] += val;
        }
      }
    }
  }
}

// ---------------- attention: one block per (window, head) -------------------
__launch_bounds__(576)
__global__ void attn_k(const unsigned short* __restrict__ qkv,
                       unsigned short* __restrict__ owin) {
  __shared__ __attribute__((aligned(16))) unsigned short Ks[144 * 72];
  __shared__ __attribute__((aligned(16))) unsigned short Vt[64 * 168];
  __shared__ __attribute__((aligned(16))) unsigned short Ps[144 * 168];
  __shared__ unsigned char gid[144];
  int bid = blockIdx.x;
  int win = bid >> 3, head = bid & 7;
  const unsigned short* qb = qkv + ((size_t)(win * 3 + 0) * 8 + head) * (144 * 64);
  const unsigned short* kb = qkv + ((size_t)(win * 3 + 1) * 8 + head) * (144 * 64);
  const unsigned short* vb = qkv + ((size_t)(win * 3 + 2) * 8 + head) * (144 * 64);
  int tid = threadIdx.x;
  {
    int row = tid >> 2, c0 = (tid & 3) << 4;
    u16x8 ka = *(const u16x8*)(kb + row * 64 + c0);
    u16x8 kc = *(const u16x8*)(kb + row * 64 + c0 + 8);
    *(u16x8*)&Ks[row * 72 + c0] = ka;
    *(u16x8*)&Ks[row * 72 + c0 + 8] = kc;
    u16x8 va = *(const u16x8*)(vb + row * 64 + c0);
    u16x8 vc = *(const u16x8*)(vb + row * 64 + c0 + 8);
    #pragma unroll
    for (int j = 0; j < 8; ++j) Vt[(c0 + j) * 168 + row] = va[j];
    #pragma unroll
    for (int j = 0; j < 8; ++j) Vt[(c0 + 8 + j) * 168 + row] = vc[j];
  }
  for (int i = tid; i < 64 * 24; i += 576) {
    int d = i / 24, m = i - d * 24;
    Vt[d * 168 + 144 + m] = 0;
  }
  for (int i = tid; i < 144 * 24; i += 576) {
    int r = i / 24, c = i - r * 24;
    Ps[r * 168 + 144 + c] = 0;
  }
  if (tid < 144) {
    int wl = win % 200;
    int c1 = wl / 100, rem = wl - c1 * 100;
    int h1 = rem / 10, w1 = rem - h1 * 10;
    int tc = tid / 72, tr = tid - tc * 72;
    int th = tr / 12, tw = tr - th * 12;
    int cs = c1 * 2 + tc, hs = h1 * 6 + th, wsp = w1 * 12 + tw;
    int rc = cs < 2 ? 0 : (cs < 3 ? 1 : 2);
    int rh = hs < 54 ? 0 : (hs < 57 ? 1 : 2);
    int rw = wsp < 108 ? 0 : (wsp < 114 ? 1 : 2);
    if (rw == 1) rw = 2;
    gid[tid] = (unsigned char)(rc * 9 + rh * 3 + rw);
  }
  __syncthreads();
  int wv = tid >> 6, l = tid & 63;
  int lane15 = l & 15, lk = (l >> 4) << 3;
  bf16x8 aq0 = *(const bf16x8*)(qb + (wv * 16 + lane15) * 64 + lk);
  bf16x8 aq1 = *(const bf16x8*)(qb + (wv * 16 + lane15) * 64 + 32 + lk);
  f32x4 sf[9];
  #pragma unroll
  for (int ct = 0; ct < 9; ++ct) {
    f32x4 z = {};
    bf16x8 b0 = *(const bf16x8*)&Ks[(ct * 16 + lane15) * 72 + lk];
    bf16x8 b1 = *(const bf16x8*)&Ks[(ct * 16 + lane15) * 72 + 32 + lk];
    z = __builtin_amdgcn_mfma_f32_16x16x32_bf16(aq0, b0, z, 0, 0, 0);
    z = __builtin_amdgcn_mfma_f32_16x16x32_bf16(aq1, b1, z, 0, 0, 0);
    sf[ct] = z;
  }
  int gi[4];
  #pragma unroll
  for (int j = 0; j < 4; ++j) gi[j] = gid[wv * 16 + ((l >> 4) << 2) + j];
  float mx[4] = {-1e30f, -1e30f, -1e30f, -1e30f};
  #pragma unroll
  for (int ct = 0; ct < 9; ++ct) {
    int gj = gid[ct * 16 + lane15];
    #pragma unroll
    for (int j = 0; j < 4; ++j) {
      float s = sf[ct][j] * 0.125f;
      if (gj != gi[j]) s = -1e30f;
      sf[ct][j] = s;
      mx[j] = fmaxf(mx[j], s);
    }
  }
  #pragma unroll
  for (int o2 = 8; o2; o2 >>= 1)
    #pragma unroll
    for (int j = 0; j < 4; ++j) mx[j] = fmaxf(mx[j], __shfl_xor(mx[j], o2));
  float sm[4] = {0.f, 0.f, 0.f, 0.f};
  #pragma unroll
  for (int ct = 0; ct < 9; ++ct)
    #pragma unroll
    for (int j = 0; j < 4; ++j) {
      float e = __expf(sf[ct][j] - mx[j]);
      sf[ct][j] = e;
      sm[j] += e;
    }
  #pragma unroll
  for (int o2 = 8; o2; o2 >>= 1)
    #pragma unroll
    for (int j = 0; j < 4; ++j) sm[j] += __shfl_xor(sm[j], o2);
  float rs[4];
  #pragma unroll
  for (int j = 0; j < 4; ++j) rs[j] = 1.0f / sm[j];
  #pragma unroll
  for (int ct = 0; ct < 9; ++ct)
    #pragma unroll
    for (int j = 0; j < 4; ++j)
      Ps[(wv * 16 + ((l >> 4) << 2) + j) * 168 + ct * 16 + lane15] =
          f2bf(sf[ct][j] * rs[j]);
  __syncthreads();
  f32x4 of[4] = {};
  #pragma unroll
  for (int ks = 0; ks < 5; ++ks) {
    bf16x8 ap = *(const bf16x8*)&Ps[(wv * 16 + lane15) * 168 + ks * 32 + lk];
    #pragma unroll
    for (int nt = 0; nt < 4; ++nt) {
      bf16x8 bv = *(const bf16x8*)&Vt[(nt * 16 + lane15) * 168 + ks * 32 + lk];
      of[nt] = __builtin_amdgcn_mfma_f32_16x16x32_bf16(ap, bv, of[nt], 0, 0, 0);
    }
  }
  unsigned short* ob = owin + (size_t)win * 144 * 512 + head * 64;
  #pragma unroll
  for (int nt = 0; nt < 4; ++nt)
    #pragma unroll
    for (int j = 0; j < 4; ++j) {
      int row = wv * 16 + ((l >> 4) << 2) + j;
      ob[(size_t)row * 512 + nt * 16 + lane15] = f2bf(of[nt][j]);
    }
}

extern "C" void kernel_launch(void* const* d_in, const int* in_sizes, int n_in,
                              void* d_out, int out_size, void* d_ws, size_t ws_size,
                              hipStream_t stream) {
  const float* x = (const float*)d_in[0];
  const float* qkv_w = (const float*)d_in[1];
  const float* qkv_b = (const float*)d_in[2];
  const float* proj_w = (const float*)d_in[3];
  const float* proj_b = (const float*)d_in[4];
  const float* n1s = (const float*)d_in[5];
  const float* n1b = (const float*)d_in[6];
  const float* n2s = (const float*)d_in[7];
  const float* n2b = (const float*)d_in[8];
  const float* w1 = (const float*)d_in[9];
  const float* b1 = (const float*)d_in[10];
  const float* w2 = (const float*)d_in[11];
  const float* b2 = (const float*)d_in[12];
  float* out = (float*)d_out;
  char* ws = (char*)d_ws;

  unsigned short* WqT = (unsigned short*)(ws);               // 1536x512
  unsigned short* WpT = (unsigned short*)(ws + 1572864);     // 512x512
  unsigned short* W1T = (unsigned short*)(ws + 2097152);     // 2048x512
  unsigned short* W2T = (unsigned short*)(ws + 4194304);     // 512x2048
  unsigned short* hwin = (unsigned short*)(ws + 6291456);    // 57600x512 (also ln2out)
  unsigned short* qkvb = (unsigned short*)(ws + 65273856);   // 57600x1536
  unsigned short* owin = (unsigned short*)(ws + 242221056);  // 57600x512
  unsigned short* mid = qkvb;                                // 57600x2048 (aliases qkv+owin)

  wtrans<<<(512 * 1536 + 255) / 256, 256, 0, stream>>>(qkv_w, WqT, 512, 1536);
  wtrans<<<(512 * 512 + 255) / 256, 256, 0, stream>>>(proj_w, WpT, 512, 512);
  wtrans<<<(512 * 2048 + 255) / 256, 256, 0, stream>>>(w1, W1T, 512, 2048);
  wtrans<<<(2048 * 512 + 255) / 256, 256, 0, stream>>>(w2, W2T, 2048, 512);
  ln_k<0><<<14400, 256, 0, stream>>>(x, n1s, n1b, hwin);
  gemmB<0><<<450 * 6, 256, 0, stream>>>(hwin, WqT, qkv_b, qkvb, nullptr, 57600, 1536, 512);
  attn_k<<<3200, 576, 0, stream>>>(qkvb, owin);
  gemmB<1><<<450 * 2, 256, 0, stream>>>(owin, WpT, proj_b, out, x, 57600, 512, 512);
  ln_k<1><<<14400, 256, 0, stream>>>(out, n2s, n2b, hwin);
  gemmB<2><<<450 * 8, 256, 0, stream>>>(hwin, W1T, b1, mid, nullptr, 57600, 2048, 512);
  gemmB<3><<<450 * 2, 256, 0, stream>>>(mid, W2T, b2, out, nullptr, 57600, 512, 2048);
}

// Round 6
// 790.697 us; speedup vs baseline: 1.1359x; 1.1359x over previous
//
#include <hip/hip_runtime.h>

typedef __attribute__((ext_vector_type(8))) short bf16x8;
typedef __attribute__((ext_vector_type(4))) float f32x4;
typedef __attribute__((ext_vector_type(8))) unsigned short u16x8;

#define BAR() __builtin_amdgcn_s_barrier()
#define VMC(n) asm volatile("s_waitcnt vmcnt(" #n ")" ::: "memory")
#define SB0() __builtin_amdgcn_sched_barrier(0)
#define WAITL(n) do { asm volatile("s_waitcnt lgkmcnt(" #n ")"); SB0(); } while (0)
#define DSRI(dst, base, imm) \
  asm volatile("ds_read_b128 %0, %1 offset:%2" : "=&v"(dst) : "v"(base), "i"(imm))

__device__ inline unsigned short f2bf(float f) {
  unsigned int u = __float_as_uint(f);
  u += 0x7fffu + ((u >> 16) & 1u);
  return (unsigned short)(u >> 16);
}

__device__ inline void gload_lds16(const void* g, void* l) {
  __builtin_amdgcn_global_load_lds(
      (const __attribute__((address_space(1))) void*)g,
      (__attribute__((address_space(3))) void*)l, 16, 0, 0);
}

// ---------------- weight transpose + bf16 cast: W[K][N] -> Wt[N][K] ----------
__global__ void wtrans(const float* __restrict__ W, unsigned short* __restrict__ Wt,
                       int K, int N) {
  int idx = blockIdx.x * 256 + threadIdx.x;
  if (idx >= K * N) return;
  int k = idx / N, n = idx - k * N;
  Wt[(size_t)n * K + k] = f2bf(W[idx]);
}

// ---------------- LayerNorm (+ optional shift/window gather), f32 -> bf16 ----
template <int MODE>
__global__ void ln_k(const float* __restrict__ x, const float* __restrict__ sc,
                     const float* __restrict__ bi, unsigned short* __restrict__ o) {
  int t = blockIdx.x * 4 + (threadIdx.x >> 6);
  int l = threadIdx.x & 63;
  size_t src;
  if (MODE == 0) {
    int b = t / 28800, r = t - b * 28800;
    int win = r / 144, tok = r - win * 144;
    int c1 = win / 100, rem = win - c1 * 100;
    int h1 = rem / 10, w1 = rem - h1 * 10;
    int tc = tok / 72, tr = tok - tc * 72;
    int th = tr / 12, tw = tr - th * 12;
    int cs = c1 * 2 + tc, hs = h1 * 6 + th, wsp = w1 * 12 + tw;
    int co = (cs + 1) & 3;
    int ho = hs + 3; if (ho >= 60) ho -= 60;
    int wo = wsp + 6; if (wo >= 120) wo -= 120;
    src = ((size_t)b * 28800 + (co * 60 + ho) * 120 + wo) * 512;
  } else {
    src = (size_t)t * 512;
  }
  const float4* xr = (const float4*)(x + src);
  float4 v0 = xr[l * 2], v1 = xr[l * 2 + 1];
  float s = v0.x + v0.y + v0.z + v0.w + v1.x + v1.y + v1.z + v1.w;
  float s2 = v0.x * v0.x + v0.y * v0.y + v0.z * v0.z + v0.w * v0.w +
             v1.x * v1.x + v1.y * v1.y + v1.z * v1.z + v1.w * v1.w;
  #pragma unroll
  for (int o2 = 32; o2; o2 >>= 1) {
    s += __shfl_xor(s, o2);
    s2 += __shfl_xor(s2, o2);
  }
  float mean = s * (1.0f / 512.0f);
  float var = s2 * (1.0f / 512.0f) - mean * mean;
  float inv = rsqrtf(var + 1e-6f);
  const float4* scp = (const float4*)sc;
  const float4* bip = (const float4*)bi;
  float4 sa = scp[l * 2], sb = scp[l * 2 + 1];
  float4 ba = bip[l * 2], bb = bip[l * 2 + 1];
  u16x8 ov;
  ov[0] = f2bf((v0.x - mean) * inv * sa.x + ba.x);
  ov[1] = f2bf((v0.y - mean) * inv * sa.y + ba.y);
  ov[2] = f2bf((v0.z - mean) * inv * sa.z + ba.z);
  ov[3] = f2bf((v0.w - mean) * inv * sa.w + ba.w);
  ov[4] = f2bf((v1.x - mean) * inv * sb.x + bb.x);
  ov[5] = f2bf((v1.y - mean) * inv * sb.y + bb.y);
  ov[6] = f2bf((v1.z - mean) * inv * sb.z + bb.z);
  ov[7] = f2bf((v1.w - mean) * inv * sb.w + bb.w);
  *(u16x8*)&o[(size_t)t * 512 + l * 8] = ov;
}

// ---------------- 256x256 bf16 MFMA GEMM, 2-phase dbuf template -------------
// A: M x K row-major bf16.  Bt: N x K row-major bf16.
// 512 threads / 8 waves (2M x 4N); wave tile 128x64; BK=64.
// LDS: 2 dbuf x (A 256x64 + B 256x64) = 128 KiB -> 1 block/CU.
// Per K-tile: STAGE(next buf, 8 gload_lds) issued FIRST (HBM latency hides
// under this tile's compute); 24 inline-asm ds_read_b128 (both k-steps);
// lgkmcnt(12) -> MFMA32(ks0); lgkmcnt(0) -> MFMA32(ks1); vmcnt(0); barrier.
// XOR swizzle (slot ^= row&7) applied store-side via pre-swizzled global
// source and read-side via swizzled ds_read address (rule 21 both-sides).
template <int EPI>
__launch_bounds__(512, 2)
__global__ void gemm2p(const unsigned short* __restrict__ A,
                       const unsigned short* __restrict__ Bt,
                       const float* __restrict__ bias, void* __restrict__ outp,
                       const float* __restrict__ res, int M, int N, int K) {
  __shared__ __attribute__((aligned(16))) unsigned short ldsb[2][32768];
  const int tid = threadIdx.x;
  const int w = tid >> 6, l = tid & 63;
  const int wm = w >> 2, wn = w & 3;
  const int lane15 = l & 15;
  const int ntile = N >> 8;
  // bijective XCD-aware swizzle (m204)
  const int nwg = gridDim.x;
  const int q = nwg >> 3, r = nwg & 7;
  const int xcd = blockIdx.x & 7, idx8 = blockIdx.x >> 3;
  const int wgid = (xcd < r ? xcd * (q + 1) : r * (q + 1) + (xcd - r) * q) + idx8;
  const int bm = wgid / ntile, bn = wgid - bm * ntile;
  const int NT = K >> 6;  // K-tiles of 64

  // ---- staging: per-thread global byte offsets, 4 rounds of 64 rows each ---
  // dest is linear (base + tid*16B); source col-slot pre-swizzled by row&7.
  int offA[4];
  {
    int rowt = tid >> 3, slot = tid & 7;
    int sl = slot ^ (rowt & 7);
    #pragma unroll
    for (int jj = 0; jj < 4; ++jj)
      offA[jj] = ((jj * 64 + rowt) * K + sl * 8) * 2;
  }
  const char* gA = (const char*)(A + (size_t)bm * 256 * K);
  const char* gB = (const char*)(Bt + (size_t)bn * 256 * K);

  // ---- read bases (swizzled): slot = (l>>4) for ks=0; ks=1 toggles bit 6 ---
  unsigned lds0 = (unsigned)(unsigned long long)
      (__attribute__((address_space(3))) void*)(void*)&ldsb[0][0];
  const int rsw = (((l >> 4) ^ (lane15 & 7)) << 4);
  unsigned rA0 = lds0 + (unsigned)((wm * 128 + lane15) * 128 + rsw);
  unsigned rB0 = lds0 + 32768u + (unsigned)((wn * 64 + lane15) * 128 + rsw);
  unsigned rA1 = rA0 + 65536u, rB1 = rB0 + 65536u;
  unsigned short* pC = &ldsb[0][0];
  unsigned short* pN = &ldsb[1][0];

  f32x4 acc[8][4] = {};
  bf16x8 af[8], bf[4], ag[8], bg[4];

  auto STAGE = [&](unsigned short* pS) {
    #pragma unroll
    for (int jj = 0; jj < 4; ++jj)
      gload_lds16(gA + offA[jj], pS + jj * 4096 + tid * 8);
    #pragma unroll
    for (int jj = 0; jj < 4; ++jj)
      gload_lds16(gB + offA[jj], pS + 16384 + jj * 4096 + tid * 8);
    gA += 128;
    gB += 128;
  };

  // prologue: stage tile 0 into buf0
  STAGE(pC);
  VMC(0);
  BAR();

  for (int t = 0; t < NT; ++t) {
    if (t < NT - 1) STAGE(pN);  // issue next-tile loads first (latency hiding)
    // ks0 fragment reads
    DSRI(af[0], rA0, 0);    DSRI(af[1], rA0, 2048);
    DSRI(af[2], rA0, 4096); DSRI(af[3], rA0, 6144);
    DSRI(af[4], rA0, 8192); DSRI(af[5], rA0, 10240);
    DSRI(af[6], rA0, 12288); DSRI(af[7], rA0, 14336);
    DSRI(bf[0], rB0, 0);    DSRI(bf[1], rB0, 2048);
    DSRI(bf[2], rB0, 4096); DSRI(bf[3], rB0, 6144);
    // ks1 fragment reads (address XOR 64 within the swizzled slot space)
    {
      unsigned rAx = rA0 ^ 64u, rBx = rB0 ^ 64u;
      DSRI(ag[0], rAx, 0);    DSRI(ag[1], rAx, 2048);
      DSRI(ag[2], rAx, 4096); DSRI(ag[3], rAx, 6144);
      DSRI(ag[4], rAx, 8192); DSRI(ag[5], rAx, 10240);
      DSRI(ag[6], rAx, 12288); DSRI(ag[7], rAx, 14336);
      DSRI(bg[0], rBx, 0);    DSRI(bg[1], rBx, 2048);
      DSRI(bg[2], rBx, 4096); DSRI(bg[3], rBx, 6144);
    }
    WAITL(12);  // ks0 operands resident; ks1 drains under MFMA ks0
    __builtin_amdgcn_s_setprio(1);
    #pragma unroll
    for (int mi = 0; mi < 8; ++mi)
      #pragma unroll
      for (int nf = 0; nf < 4; ++nf)
        acc[mi][nf] = __builtin_amdgcn_mfma_f32_16x16x32_bf16(
            af[mi], bf[nf], acc[mi][nf], 0, 0, 0);
    __builtin_amdgcn_s_setprio(0);
    WAITL(0);
    __builtin_amdgcn_s_setprio(1);
    #pragma unroll
    for (int mi = 0; mi < 8; ++mi)
      #pragma unroll
      for (int nf = 0; nf < 4; ++nf)
        acc[mi][nf] = __builtin_amdgcn_mfma_f32_16x16x32_bf16(
            ag[mi], bg[nf], acc[mi][nf], 0, 0, 0);
    __builtin_amdgcn_s_setprio(0);
    VMC(0);  // next buf fully staged (issued a whole tile of compute ago)
    BAR();
    { unsigned tt = rA0; rA0 = rA1; rA1 = tt; }
    { unsigned tt = rB0; rB0 = rB1; rB1 = tt; }
    { unsigned short* tp = pC; pC = pN; pN = tp; }
  }

  // ---------------- epilogue ----------------
  float* outf = (float*)outp;
  unsigned short* outh = (unsigned short*)outp;
  #pragma unroll
  for (int mi = 0; mi < 8; ++mi) {
    #pragma unroll
    for (int j = 0; j < 4; ++j) {
      int grow = bm * 256 + wm * 128 + mi * 16 + ((l >> 4) << 2) + j;
      int win = 0, tok = 0;
      size_t rowbase = 0;
      if constexpr (EPI == 0) {
        win = grow / 144;
        tok = grow - win * 144;
      } else if constexpr (EPI == 1) {
        win = grow / 144;
        tok = grow - win * 144;
        int b = win / 200, wl = win - b * 200;
        int c1 = wl / 100, rem = wl - c1 * 100;
        int h1 = rem / 10, w1 = rem - h1 * 10;
        int tc = tok / 72, tr = tok - tc * 72;
        int th = tr / 12, tw = tr - th * 12;
        int cs = c1 * 2 + tc, hs = h1 * 6 + th, wsp = w1 * 12 + tw;
        int co = (cs + 1) & 3;
        int ho = hs + 3; if (ho >= 60) ho -= 60;
        int wo = wsp + 6; if (wo >= 120) wo -= 120;
        rowbase = ((size_t)b * 28800 + (co * 60 + ho) * 120 + wo) * 512;
      }
      #pragma unroll
      for (int nf = 0; nf < 4; ++nf) {
        int gcol = bn * 256 + wn * 64 + nf * 16 + lane15;
        float val = acc[mi][nf][j] + bias[gcol];
        if constexpr (EPI == 0) {
          int which = gcol >> 9, hd = (gcol >> 6) & 7, dh = gcol & 63;
          outh[(((size_t)(win * 3 + which) * 8 + hd) * 144 + tok) * 64 + dh] = f2bf(val);
        } else if constexpr (EPI == 1) {
          size_t oi = rowbase + gcol;
          outf[oi] = res[oi] + val;
        } else if constexpr (EPI == 2) {
          float u = 0.7978845608f * (val + 0.044715f * val * val * val);
          float g = val / (1.0f + __expf(-2.0f * u));
          outh[(size_t)grow * N + gcol] = f2bf(g);
        } else {
          size_t oi = (size_t)grow * N + gcol;
          outf[oi] += val;
        }
      }
    }
  }
}

// ---------------- attention: one block per (window, head) -------------------
__launch_bounds__(576)
__global__ void attn_k(const unsigned short* __restrict__ qkv,
                       unsigned short* __restrict__ owin) {
  __shared__ __attribute__((aligned(16))) unsigned short Ks[144 * 72];
  __shared__ __attribute__((aligned(16))) unsigned short Vt[64 * 168];
  __shared__ __attribute__((aligned(16))) unsigned short Ps[144 * 168];
  __shared__ unsigned char gid[144];
  int bid = blockIdx.x;
  int win = bid >> 3, head = bid & 7;
  const unsigned short* qb = qkv + ((size_t)(win * 3 + 0) * 8 + head) * (144 * 64);
  const unsigned short* kb = qkv + ((size_t)(win * 3 + 1) * 8 + head) * (144 * 64);
  const unsigned short* vb = qkv + ((size_t)(win * 3 + 2) * 8 + head) * (144 * 64);
  int tid = threadIdx.x;
  {
    int row = tid >> 2, c0 = (tid & 3) << 4;
    u16x8 ka = *(const u16x8*)(kb + row * 64 + c0);
    u16x8 kc = *(const u16x8*)(kb + row * 64 + c0 + 8);
    *(u16x8*)&Ks[row * 72 + c0] = ka;
    *(u16x8*)&Ks[row * 72 + c0 + 8] = kc;
    u16x8 va = *(const u16x8*)(vb + row * 64 + c0);
    u16x8 vc = *(const u16x8*)(vb + row * 64 + c0 + 8);
    #pragma unroll
    for (int j = 0; j < 8; ++j) Vt[(c0 + j) * 168 + row] = va[j];
    #pragma unroll
    for (int j = 0; j < 8; ++j) Vt[(c0 + 8 + j) * 168 + row] = vc[j];
  }
  for (int i = tid; i < 64 * 24; i += 576) {
    int d = i / 24, m = i - d * 24;
    Vt[d * 168 + 144 + m] = 0;
  }
  for (int i = tid; i < 144 * 24; i += 576) {
    int r = i / 24, c = i - r * 24;
    Ps[r * 168 + 144 + c] = 0;
  }
  if (tid < 144) {
    int wl = win % 200;
    int c1 = wl / 100, rem = wl - c1 * 100;
    int h1 = rem / 10, w1 = rem - h1 * 10;
    int tc = tid / 72, tr = tid - tc * 72;
    int th = tr / 12, tw = tr - th * 12;
    int cs = c1 * 2 + tc, hs = h1 * 6 + th, wsp = w1 * 12 + tw;
    int rc = cs < 2 ? 0 : (cs < 3 ? 1 : 2);
    int rh = hs < 54 ? 0 : (hs < 57 ? 1 : 2);
    int rw = wsp < 108 ? 0 : (wsp < 114 ? 1 : 2);
    if (rw == 1) rw = 2;
    gid[tid] = (unsigned char)(rc * 9 + rh * 3 + rw);
  }
  __syncthreads();
  int wv = tid >> 6, l = tid & 63;
  int lane15 = l & 15, lk = (l >> 4) << 3;
  bf16x8 aq0 = *(const bf16x8*)(qb + (wv * 16 + lane15) * 64 + lk);
  bf16x8 aq1 = *(const bf16x8*)(qb + (wv * 16 + lane15) * 64 + 32 + lk);
  f32x4 sf[9];
  #pragma unroll
  for (int ct = 0; ct < 9; ++ct) {
    f32x4 z = {};
    bf16x8 b0 = *(const bf16x8*)&Ks[(ct * 16 + lane15) * 72 + lk];
    bf16x8 b1 = *(const bf16x8*)&Ks[(ct * 16 + lane15) * 72 + 32 + lk];
    z = __builtin_amdgcn_mfma_f32_16x16x32_bf16(aq0, b0, z, 0, 0, 0);
    z = __builtin_amdgcn_mfma_f32_16x16x32_bf16(aq1, b1, z, 0, 0, 0);
    sf[ct] = z;
  }
  int gi[4];
  #pragma unroll
  for (int j = 0; j < 4; ++j) gi[j] = gid[wv * 16 + ((l >> 4) << 2) + j];
  float mx[4] = {-1e30f, -1e30f, -1e30f, -1e30f};
  #pragma unroll
  for (int ct = 0; ct < 9; ++ct) {
    int gj = gid[ct * 16 + lane15];
    #pragma unroll
    for (int j = 0; j < 4; ++j) {
      float s = sf[ct][j] * 0.125f;
      if (gj != gi[j]) s = -1e30f;
      sf[ct][j] = s;
      mx[j] = fmaxf(mx[j], s);
    }
  }
  #pragma unroll
  for (int o2 = 8; o2; o2 >>= 1)
    #pragma unroll
    for (int j = 0; j < 4; ++j) mx[j] = fmaxf(mx[j], __shfl_xor(mx[j], o2));
  float sm[4] = {0.f, 0.f, 0.f, 0.f};
  #pragma unroll
  for (int ct = 0; ct < 9; ++ct)
    #pragma unroll
    for (int j = 0; j < 4; ++j) {
      float e = __expf(sf[ct][j] - mx[j]);
      sf[ct][j] = e;
      sm[j] += e;
    }
  #pragma unroll
  for (int o2 = 8; o2; o2 >>= 1)
    #pragma unroll
    for (int j = 0; j < 4; ++j) sm[j] += __shfl_xor(sm[j], o2);
  float rs[4];
  #pragma unroll
  for (int j = 0; j < 4; ++j) rs[j] = 1.0f / sm[j];
  #pragma unroll
  for (int ct = 0; ct < 9; ++ct)
    #pragma unroll
    for (int j = 0; j < 4; ++j)
      Ps[(wv * 16 + ((l >> 4) << 2) + j) * 168 + ct * 16 + lane15] =
          f2bf(sf[ct][j] * rs[j]);
  __syncthreads();
  f32x4 of[4] = {};
  #pragma unroll
  for (int ks = 0; ks < 5; ++ks) {
    bf16x8 ap = *(const bf16x8*)&Ps[(wv * 16 + lane15) * 168 + ks * 32 + lk];
    #pragma unroll
    for (int nt = 0; nt < 4; ++nt) {
      bf16x8 bv = *(const bf16x8*)&Vt[(nt * 16 + lane15) * 168 + ks * 32 + lk];
      of[nt] = __builtin_amdgcn_mfma_f32_16x16x32_bf16(ap, bv, of[nt], 0, 0, 0);
    }
  }
  unsigned short* ob = owin + (size_t)win * 144 * 512 + head * 64;
  #pragma unroll
  for (int nt = 0; nt < 4; ++nt)
    #pragma unroll
    for (int j = 0; j < 4; ++j) {
      int row = wv * 16 + ((l >> 4) << 2) + j;
      ob[(size_t)row * 512 + nt * 16 + lane15] = f2bf(of[nt][j]);
    }
}

extern "C" void kernel_launch(void* const* d_in, const int* in_sizes, int n_in,
                              void* d_out, int out_size, void* d_ws, size_t ws_size,
                              hipStream_t stream) {
  const float* x = (const float*)d_in[0];
  const float* qkv_w = (const float*)d_in[1];
  const float* qkv_b = (const float*)d_in[2];
  const float* proj_w = (const float*)d_in[3];
  const float* proj_b = (const float*)d_in[4];
  const float* n1s = (const float*)d_in[5];
  const float* n1b = (const float*)d_in[6];
  const float* n2s = (const float*)d_in[7];
  const float* n2b = (const float*)d_in[8];
  const float* w1 = (const float*)d_in[9];
  const float* b1 = (const float*)d_in[10];
  const float* w2 = (const float*)d_in[11];
  const float* b2 = (const float*)d_in[12];
  float* out = (float*)d_out;
  char* ws = (char*)d_ws;

  unsigned short* WqT = (unsigned short*)(ws);               // 1536x512
  unsigned short* WpT = (unsigned short*)(ws + 1572864);     // 512x512
  unsigned short* W1T = (unsigned short*)(ws + 2097152);     // 2048x512
  unsigned short* W2T = (unsigned short*)(ws + 4194304);     // 512x2048
  unsigned short* hwin = (unsigned short*)(ws + 6291456);    // 57600x512 (also ln2out)
  unsigned short* qkvb = (unsigned short*)(ws + 65273856);   // 57600x1536
  unsigned short* owin = (unsigned short*)(ws + 242221056);  // 57600x512
  unsigned short* mid = qkvb;                                // 57600x2048 (aliases qkv+owin)

  wtrans<<<(512 * 1536 + 255) / 256, 256, 0, stream>>>(qkv_w, WqT, 512, 1536);
  wtrans<<<(512 * 512 + 255) / 256, 256, 0, stream>>>(proj_w, WpT, 512, 512);
  wtrans<<<(512 * 2048 + 255) / 256, 256, 0, stream>>>(w1, W1T, 512, 2048);
  wtrans<<<(2048 * 512 + 255) / 256, 256, 0, stream>>>(w2, W2T, 2048, 512);
  ln_k<0><<<14400, 256, 0, stream>>>(x, n1s, n1b, hwin);
  gemm2p<0><<<225 * 6, 512, 0, stream>>>(hwin, WqT, qkv_b, qkvb, nullptr, 57600, 1536, 512);
  attn_k<<<3200, 576, 0, stream>>>(qkvb, owin);
  gemm2p<1><<<225 * 2, 512, 0, stream>>>(owin, WpT, proj_b, out, x, 57600, 512, 512);
  ln_k<1><<<14400, 256, 0, stream>>>(out, n2s, n2b, hwin);
  gemm2p<2><<<225 * 8, 512, 0, stream>>>(hwin, W1T, b1, mid, nullptr, 57600, 2048, 512);
  gemm2p<3><<<225 * 2, 512, 0, stream>>>(mid, W2T, b2, out, nullptr, 57600, 512, 2048);
}